// Round 8
// baseline (137.278 us; speedup 1.0000x reference)
//
#include <hip/hip_runtime.h>
#include <math.h>

#define CHANNEL 128
#define NEG_INF (-1e30f)
#define P2STRIDE 132   // 128 + 4 pad floats; 132*4=528 B keeps 16B alignment per row

__device__ __forceinline__ float dot4(float4 a, float4 b) {
    return a.x * b.x + a.y * b.y + a.z * b.z + a.w * b.w;
}

// blocks [0,R): prep  P2[r] = (W W^T relw[r]^T)/16, rel_norm[r] = ||relw[r]||^2
// blocks [R,..): count degrees + per-edge rank (atomic return order)
__global__ void __launch_bounds__(256) prep_count_kernel(
    const float* __restrict__ relw, const float* __restrict__ W,
    const int* __restrict__ eidx, float* __restrict__ P2,
    float* __restrict__ rel_norm, int* __restrict__ deg,
    unsigned short* __restrict__ rank, int E, int R)
{
    int b = blockIdx.x;
    if (b < R) {
        __shared__ float rw[CHANNEL];
        __shared__ float kr[CHANNEL];
        __shared__ float red[CHANNEL];
        int c = threadIdx.x;
        int j = b;
        if (c < CHANNEL) {
            float v = relw[j * CHANNEL + c];
            rw[c] = v;
            red[c] = v * v;
        }
        __syncthreads();
        for (int s = CHANNEL / 2; s > 0; s >>= 1) {
            if (c < s) red[c] += red[c + s];
            __syncthreads();
        }
        if (c == 0) rel_norm[j] = red[0];
        if (c < CHANNEL) {
            float acc = 0.f;
            for (int k = 0; k < CHANNEL; ++k) acc += rw[k] * W[k * CHANNEL + c];
            kr[c] = acc;
        }
        __syncthreads();
        if (c < CHANNEL) {
            float acc2 = 0.f;
            for (int cc = 0; cc < CHANNEL; ++cc) acc2 += W[c * CHANNEL + cc] * kr[cc];
            P2[j * CHANNEL + c] = acc2 * 0.0625f;
        }
    } else {
        int e = (b - R) * 256 + threadIdx.x;
        if (e < E) rank[e] = (unsigned short)atomicAdd(deg + eidx[e], 1);
    }
}

// per-block (256) exclusive scan of deg; raw = local exclusive, partial = block totals
__global__ void scan1_kernel(const int* __restrict__ deg, int* __restrict__ raw,
                             int* __restrict__ partial, int N) {
    __shared__ int sh[256];
    int t = threadIdx.x;
    int i = blockIdx.x * 256 + t;
    int v = (i < N) ? deg[i] : 0;
    sh[t] = v;
    __syncthreads();
    for (int off = 1; off < 256; off <<= 1) {
        int u = (t >= off) ? sh[t - off] : 0;
        __syncthreads();
        sh[t] += u;
        __syncthreads();
    }
    if (i < N) raw[i] = sh[t] - v;
    if (t == 255) partial[blockIdx.x] = sh[255];
}

// single block: exclusive scan of block totals (nblk <= 1024)
__global__ void scan2_kernel(int* __restrict__ partial, int nblk) {
    __shared__ int sh[1024];
    int t = threadIdx.x;
    int v = (t < nblk) ? partial[t] : 0;
    sh[t] = v;
    __syncthreads();
    for (int off = 1; off < 1024; off <<= 1) {
        int u = (t >= off) ? sh[t - off] : 0;
        __syncthreads();
        sh[t] += u;
        __syncthreads();
    }
    if (t < nblk) partial[t] = sh[t] - v;
}

// atomic-free placement: recs[start(h) + rank[e]] = { tail | type<<20, edge_id }
__global__ void place_kernel(const int* __restrict__ eidx, const int* __restrict__ etype,
                             const int* __restrict__ raw, const int* __restrict__ partial,
                             const unsigned short* __restrict__ rank,
                             int2* __restrict__ recs, int E) {
    int e = blockIdx.x * 256 + threadIdx.x;
    if (e >= E) return;
    int h = eidx[e];
    int t = eidx[E + e];
    int r = etype[e] - 1;
    int pos = raw[h] + partial[h >> 8] + (int)rank[e];
    recs[pos] = make_int2(t | (r << 20), e);
}

struct Row4 { float4 t0, t1, t2, t3; int typ; };

// 512 thr = 8 waves = 8 heads per block; P2 + rel_norm staged in LDS;
// tail rows: the only global gather, depth-3 pipelined, guarded (no phantom issues)
__global__ void __launch_bounds__(512) main_kernel(
        const float* __restrict__ ent, const float* __restrict__ P2,
        const float* __restrict__ rel_norm, const int* __restrict__ raw,
        const int* __restrict__ partial, const int2* __restrict__ recs,
        float* __restrict__ out, int N, int E) {
    __shared__ float p2s[50 * P2STRIDE + 56];
    float* rels = p2s + 50 * P2STRIDE;
    for (int i = threadIdx.x; i < 50 * CHANNEL; i += 512) {
        int r = i >> 7, k = i & 127;
        p2s[r * P2STRIDE + k] = P2[i];
    }
    for (int i = threadIdx.x; i < 50; i += 512) rels[i] = rel_norm[i];
    __syncthreads();

    int wid = blockIdx.x * 8 + (threadIdx.x >> 6);
    if (wid >= N) return;
    int lane = threadIdx.x & 63;

    int s0 = raw[wid] + partial[wid >> 8];
    int nxt = (wid + 1 < N) ? (raw[wid + 1] + partial[(wid + 1) >> 8]) : E;
    int deg_h = nxt - s0;
    if (deg_h == 0) return;

    const float4* hp = (const float4*)(ent + (size_t)wid * CHANNEL);
    const float4* p2v = (const float4*)p2s;   // row r at p2v + r*33

    if (deg_h <= 64) {
        int grp = lane >> 3;   // edge slot 0..7
        int sub = lane & 7;    // row eighth
        float4 h0 = hp[sub], h1 = hp[sub + 8], h2 = hp[sub + 16], h3 = hp[sub + 24];

        int lc = lane < deg_h ? lane : deg_h - 1;
        int2 rc = recs[s0 + lc];
        int iters = (deg_h + 7) >> 3;

        auto issue = [&](int g) -> Row4 {
            Row4 s;
            if (g < iters) {   // uniform branch: NO phantom loads past the end
                int e = 8 * g + grp;
                int ec = e < deg_h ? e : deg_h - 1;
                int rcx = __shfl(rc.x, ec);
                int tail = rcx & 0xFFFFF;
                s.typ = rcx >> 20;
                const float4* tp = (const float4*)(ent + (size_t)tail * CHANNEL);
                s.t0 = tp[sub]; s.t1 = tp[sub + 8]; s.t2 = tp[sub + 16]; s.t3 = tp[sub + 24];
            } else {
                s.typ = 0;
                s.t0 = s.t1 = s.t2 = s.t3 = make_float4(0.f, 0.f, 0.f, 0.f);
            }
            return s;
        };

        float d1c = 0.f, d2c = 0.f;
        auto compute = [&](int g, const Row4& s) {
            const float4* pr = p2v + s.typ * 33;
            float4 r0 = pr[sub], r1 = pr[sub + 8], r2 = pr[sub + 16], r3 = pr[sub + 24];
            float d1 = dot4(h0, s.t0) + dot4(h1, s.t1) + dot4(h2, s.t2) + dot4(h3, s.t3);
            float d2 = dot4(h0, r0) + dot4(h1, r1) + dot4(h2, r2) + dot4(h3, r3);
#pragma unroll
            for (int m = 1; m <= 4; m <<= 1) {
                d1 += __shfl_xor(d1, m);
                d2 += __shfl_xor(d2, m);
            }
            int srcl = (lane & 7) * 8;
            float td1 = __shfl(d1, srcl);
            float td2 = __shfl(d2, srcl);
            if ((lane >> 3) == g) { d1c = td1; d2c = td2; }
        };

        Row4 A = issue(0);
        Row4 B = issue(1);
        int g = 0;
        for (;;) {
            Row4 C = issue(g + 2);
            compute(g, A);
            if (++g >= iters) break;
            A = issue(g + 2);
            compute(g, B);
            if (++g >= iters) break;
            B = issue(g + 2);
            compute(g, C);
            if (++g >= iters) break;
        }

        bool valid = lane < deg_h;
        int typc = rc.x >> 20;
        int eidc = rc.y;
        // softmax 1 over d2
        float m1 = valid ? d2c : NEG_INF;
#pragma unroll
        for (int m = 32; m; m >>= 1) m1 = fmaxf(m1, __shfl_xor(m1, m));
        float e1 = valid ? expf(d2c - m1) : 0.f;
        float s1 = e1;
#pragma unroll
        for (int m = 32; m; m >>= 1) s1 += __shfl_xor(s1, m);
        float rs = e1 / s1;
        // trip score + softmax 2
        float stv = d1c + rs * rs * rels[typc];
        float m2 = valid ? stv : NEG_INF;
#pragma unroll
        for (int m = 32; m; m >>= 1) m2 = fmaxf(m2, __shfl_xor(m2, m));
        float e2 = valid ? expf(stv - m2) : 0.f;
        float s2 = e2;
#pragma unroll
        for (int m = 32; m; m >>= 1) s2 += __shfl_xor(s2, m);
        if (valid) out[eidc] = e2 / s2;
    } else {
        // slow path (deg > 64; ~never for this distribution): multi-sweep,
        // uses out[] itself as per-edge scratch — correct, not fast
        int grp = lane >> 4;
        int sub = lane & 15;
        float4 H0 = hp[sub], H1 = hp[sub + 16];

        // sweep 1: d1 -> out[eid]; running max of d2
        float pm1 = NEG_INF;
        for (int k0 = 0; k0 < deg_h; k0 += 4) {
            int idx = k0 + grp;
            bool act = idx < deg_h;
            int j = s0 + (act ? idx : 0);
            int2 rc = recs[j];
            int tail = rc.x & 0xFFFFF;
            int typ = rc.x >> 20;
            const float4* tp = (const float4*)(ent + (size_t)tail * CHANNEL);
            const float4* pr = p2v + typ * 33;
            float4 t0 = tp[sub], t1 = tp[sub + 16];
            float4 r0 = pr[sub], r1 = pr[sub + 16];
            float d1 = dot4(H0, t0) + dot4(H1, t1);
            float d2 = dot4(H0, r0) + dot4(H1, r1);
#pragma unroll
            for (int m = 1; m <= 8; m <<= 1) {
                d1 += __shfl_xor(d1, m);
                d2 += __shfl_xor(d2, m);
            }
            if (act) {
                if (sub == 0) out[rc.y] = d1;
                pm1 = fmaxf(pm1, d2);
            }
        }
        pm1 = fmaxf(pm1, __shfl_xor(pm1, 16));
        pm1 = fmaxf(pm1, __shfl_xor(pm1, 32));
        float m1 = pm1;

        // sweep 2: s1 (recompute d2 from LDS)
        float s1p = 0.f;
        for (int k0 = 0; k0 < deg_h; k0 += 4) {
            int idx = k0 + grp;
            bool act = idx < deg_h;
            int j = s0 + (act ? idx : 0);
            int typ = recs[j].x >> 20;
            const float4* pr = p2v + typ * 33;
            float4 r0 = pr[sub], r1 = pr[sub + 16];
            float d2 = dot4(H0, r0) + dot4(H1, r1);
#pragma unroll
            for (int m = 1; m <= 8; m <<= 1) d2 += __shfl_xor(d2, m);
            if (act && sub == 0) s1p += expf(d2 - m1);
        }
#pragma unroll
        for (int m = 32; m; m >>= 1) s1p += __shfl_xor(s1p, m);
        float s1 = s1p;

        // sweep 3: stv = d1 + rs^2*rel_norm -> out[eid]; track m2
        float pm2 = NEG_INF;
        for (int k0 = 0; k0 < deg_h; k0 += 4) {
            int idx = k0 + grp;
            bool act = idx < deg_h;
            int j = s0 + (act ? idx : 0);
            int2 rc = recs[j];
            int typ = rc.x >> 20;
            const float4* pr = p2v + typ * 33;
            float4 r0 = pr[sub], r1 = pr[sub + 16];
            float d2 = dot4(H0, r0) + dot4(H1, r1);
#pragma unroll
            for (int m = 1; m <= 8; m <<= 1) d2 += __shfl_xor(d2, m);
            if (act && sub == 0) {
                float e1 = expf(d2 - m1);
                float rsv = e1 / s1;
                float stv = out[rc.y] + rsv * rsv * rels[typ];
                out[rc.y] = stv;
                pm2 = fmaxf(pm2, stv);
            }
        }
#pragma unroll
        for (int m = 32; m; m >>= 1) pm2 = fmaxf(pm2, __shfl_xor(pm2, m));
        float m2 = pm2;

        // sweep 4: s2
        float s2p = 0.f;
        for (int k = lane; k < deg_h; k += 64)
            s2p += expf(out[recs[s0 + k].y] - m2);
#pragma unroll
        for (int m = 32; m; m >>= 1) s2p += __shfl_xor(s2p, m);
        float s2 = s2p;

        // sweep 5: normalize in place
        for (int k = lane; k < deg_h; k += 64) {
            int eid = recs[s0 + k].y;
            out[eid] = expf(out[eid] - m2) / s2;
        }
    }
}

extern "C" void kernel_launch(void* const* d_in, const int* in_sizes, int n_in,
                              void* d_out, int out_size, void* d_ws, size_t ws_size,
                              hipStream_t stream) {
    const float* ent   = (const float*)d_in[0];
    const float* relw  = (const float*)d_in[2];
    const float* W     = (const float*)d_in[3];
    const int*   eidx  = (const int*)d_in[4];
    const int*   etype = (const int*)d_in[5];
    float* out = (float*)d_out;

    const int E = in_sizes[5];
    const int N = in_sizes[0] / CHANNEL;
    const int R = in_sizes[2] / CHANNEL;

    char* base = (char*)d_ws;
    auto alloc = [&](size_t bytes) {
        char* p = base;
        base += (bytes + 15) & ~(size_t)15;
        return p;
    };
    int*    deg      = (int*)alloc((size_t)N * 4);
    int*    raw      = (int*)alloc((size_t)N * 4);
    int*    partial  = (int*)alloc(1024 * 4);
    int2*   recs     = (int2*)alloc((size_t)E * 8);
    float*  P2       = (float*)alloc((size_t)R * CHANNEL * 4);
    float*  rel_norm = (float*)alloc((size_t)R * 4);
    unsigned short* rank = (unsigned short*)alloc((size_t)E * 2);

    hipMemsetAsync(deg, 0, (size_t)N * 4, stream);

    int ceblk = (E + 255) / 256;
    prep_count_kernel<<<R + ceblk, 256, 0, stream>>>(relw, W, eidx, P2, rel_norm,
                                                     deg, rank, E, R);

    int nblk = (N + 255) / 256;  // 157 for N=40000; must be <= 1024
    scan1_kernel<<<nblk, 256, 0, stream>>>(deg, raw, partial, N);
    scan2_kernel<<<1, 1024, 0, stream>>>(partial, nblk);

    place_kernel<<<ceblk, 256, 0, stream>>>(eidx, etype, raw, partial, rank, recs, E);

    int bm = (N + 7) / 8;  // 8 waves per block, one wave per head
    main_kernel<<<bm, 512, 0, stream>>>(ent, P2, rel_norm, raw, partial, recs, out, N, E);
}